// Round 1
// 558.154 us; speedup vs baseline: 1.1539x; 1.1539x over previous
//
#include <hip/hip_runtime.h>

// ---------------- common helpers ----------------

typedef __attribute__((ext_vector_type(8))) short s16x8;    // 8 x bf16 (4 VGPRs)
typedef __attribute__((ext_vector_type(16))) float f32x16;  // 32x32 MFMA accumulator

__device__ __forceinline__ unsigned short f2bf(float f) {
  union { float f; unsigned u; } v; v.f = f;
  unsigned r = v.u + 0x7fffu + ((v.u >> 16) & 1u);   // round-to-nearest-even
  return (unsigned short)(r >> 16);
}
__device__ __forceinline__ float bf2f(unsigned short h) {
  union { unsigned u; float f; } v; v.u = ((unsigned)h) << 16; return v.f;
}
__device__ __forceinline__ void gload_lds16(const void* g, void* l) {
  __builtin_amdgcn_global_load_lds(
      (const __attribute__((address_space(1))) void*)g,
      (__attribute__((address_space(3))) void*)l, 16, 0, 0);
}

// ---------------- fp32 -> bf16 convert (weights) ----------------

__global__ void conv_bf16(const float4* __restrict__ src, ushort4* __restrict__ dst, int n4) {
  int i = blockIdx.x * blockDim.x + threadIdx.x;
  if (i >= n4) return;
  float4 v = src[i];
  ushort4 o;
  o.x = f2bf(v.x); o.y = f2bf(v.y); o.z = f2bf(v.z); o.w = f2bf(v.w);
  dst[i] = o;
}

// ---------------- fused time-shift mix -> xk, xv, xr (bf16) ----------------

__global__ void prep_mix3(const float4* __restrict__ hidden,
                          const float4* __restrict__ tmk,
                          const float4* __restrict__ tmv,
                          const float4* __restrict__ tmr,
                          ushort4* __restrict__ xk, ushort4* __restrict__ xv,
                          ushort4* __restrict__ xr,
                          int S, int H4, long long total4) {
  long long i = (long long)blockIdx.x * blockDim.x + threadIdx.x;
  if (i >= total4) return;
  int h4 = (int)(i % H4);
  long long sb = i / H4;          // b*S + s
  int s = (int)(sb % S);
  float4 cur = hidden[i];
  float4 prev = make_float4(0.f, 0.f, 0.f, 0.f);
  if (s > 0) prev = hidden[i - H4];
  float4 mk = tmk[h4], mv = tmv[h4], mr = tmr[h4];
  ushort4 ok, ov, orr;
  ok.x = f2bf(cur.x * mk.x + prev.x * (1.f - mk.x));
  ok.y = f2bf(cur.y * mk.y + prev.y * (1.f - mk.y));
  ok.z = f2bf(cur.z * mk.z + prev.z * (1.f - mk.z));
  ok.w = f2bf(cur.w * mk.w + prev.w * (1.f - mk.w));
  ov.x = f2bf(cur.x * mv.x + prev.x * (1.f - mv.x));
  ov.y = f2bf(cur.y * mv.y + prev.y * (1.f - mv.y));
  ov.z = f2bf(cur.z * mv.z + prev.z * (1.f - mv.z));
  ov.w = f2bf(cur.w * mv.w + prev.w * (1.f - mv.w));
  orr.x = f2bf(cur.x * mr.x + prev.x * (1.f - mr.x));
  orr.y = f2bf(cur.y * mr.y + prev.y * (1.f - mr.y));
  orr.z = f2bf(cur.z * mr.z + prev.z * (1.f - mr.z));
  orr.w = f2bf(cur.w * mr.w + prev.w * (1.f - mr.w));
  xk[i] = ok; xv[i] = ov; xr[i] = orr;
}

// ---------------- bf16 NT GEMM: C[M,N] = A[M,K] * B[N,K]^T ----------------
// 256x256 tile, BK=32, 8 waves (2M x 4N, per-wave 128x64 via 4x2 of 32x32x16
// MFMA). Ring-of-4 LDS K-tile slots (128 KiB) + counted s_waitcnt vmcnt(8):
// tiles t+1..t+3 stay in flight across raw s_barriers (T3/T4). Per iteration:
// 12 ds_read_b128 | stage 4 global_load_lds (tile t+3) | vmcnt(8) | barrier |
// setprio(1) 16 MFMA setprio(0) | barrier. Epilogue drains vmcnt 8->4->0.
// LDS swizzle: chunk ^= (row>>1)&3 on 16B chunks of the 64B row -> every
// 8-lane ds_read_b128 group covers all 8 LDS 16B-slots (conflict-free).
// global_load_lds dest stays LINEAR (lane*16); inverse swizzle is applied to
// the per-lane GLOBAL source address (both-sides-or-neither rule).
// Safety argument (no WAR race): tile t+3 -> slot (t+3)&3 = (t-1)&3 is issued
// only after barrier-2 of iteration t-1, by which point every wave's ds_reads
// of tile t-1 have completed (compiler lgkmcnt precedes its MFMA cluster,
// which precedes that barrier). vmcnt(8) at iter t with <=12 outstanding
// (tiles t+1,t+2,t+3) lands exactly tile t+1 before iter t+1 reads it.
// EPI: 0 = fp32; 1 = sigmoid bf16; 2 = bf16.

template <int EPI>
__global__ __launch_bounds__(512) void gemm_bt(
    const unsigned short* __restrict__ A, const unsigned short* __restrict__ B,
    float* __restrict__ Cf, unsigned short* __restrict__ Cb,
    int M, int N, int K) {
  // 4 ring slots x (A 256x32 | B 256x32) bf16 = 4 x 32 KiB = 128 KiB
  __shared__ unsigned short lds[4][16384];

  const int tid = threadIdx.x;
  const int wave = tid >> 6;
  const int lane = tid & 63;

  // XCD-aware bijective block swizzle: nwg % 8 == 0 (256 blocks). Each XCD
  // gets a contiguous m-run sharing one B panel (1 MiB, L2-resident).
  const int nwg = (int)gridDim.x;
  const int q = nwg >> 3;
  const int wg = (blockIdx.x & 7) * q + (blockIdx.x >> 3);
  const int GM = M >> 8;
  const int bm = (wg % GM) * 256;
  const int bn = (wg / GM) * 256;

  const int wm = (wave >> 2) * 128;    // wave's 128x64 sub-tile
  const int wn = (wave & 3) * 64;
  const int lrow = lane & 31;
  const int lq = lane >> 5;            // k-chunk half selector (0/1)

  f32x16 acc[4][2] = {};

  // ---- staging addresses (per thread: 4 x 16B per K-tile) ----
  // round covers 128 rows x 64B; thread t: row = t>>2, dest chunk = t&3.
  // inverse swizzle on global source: src chunk = (t&3) ^ ((row>>1)&3).
  const int srow = tid >> 2;
  const int sg = ((tid & 3) ^ ((srow >> 1) & 3)) * 8;
  const unsigned short* gA0 = A + (long long)(bm + srow) * K + sg;
  const unsigned short* gA1 = A + (long long)(bm + 128 + srow) * K + sg;
  const unsigned short* gB0 = B + (long long)(bn + srow) * K + sg;
  const unsigned short* gB1 = B + (long long)(bn + 128 + srow) * K + sg;

#define STAGE(sl)                                              \
  {                                                            \
    unsigned short* dst = &lds[sl][0] + wave * 512;            \
    gload_lds16(gA0, dst);                                     \
    gload_lds16(gA1, dst + 4096);                              \
    gload_lds16(gB0, dst + 8192);                              \
    gload_lds16(gB1, dst + 12288);                             \
    gA0 += 32; gA1 += 32; gB0 += 32; gB1 += 32;                \
  }

  // ---- fragment LDS offsets (shorts, loop-invariant) ----
  // row R, chunk c (16B) -> R*32 + (c ^ ((R>>1)&3))*8
  int offA[4][2], offB[2][2];
#pragma unroll
  for (int mt = 0; mt < 4; ++mt)
#pragma unroll
    for (int h = 0; h < 2; ++h) {
      int R = wm + mt * 32 + lrow;
      int c = h * 2 + lq;
      offA[mt][h] = R * 32 + ((c ^ ((R >> 1) & 3)) * 8);
    }
#pragma unroll
  for (int nt = 0; nt < 2; ++nt)
#pragma unroll
    for (int h = 0; h < 2; ++h) {
      int Cc = wn + nt * 32 + lrow;
      int c = h * 2 + lq;
      offB[nt][h] = 8192 + Cc * 32 + ((c ^ ((Cc >> 1) & 3)) * 8);
    }

  const int NT = K >> 5;   // K / 32 (= 64 here, >= 4 required)

  // ---- prologue: stage tiles 0,1,2; wait tile 0 landed (8 still in flight)
  STAGE(0);
  STAGE(1);
  STAGE(2);
  asm volatile("s_waitcnt vmcnt(8)" ::: "memory");
  __builtin_amdgcn_sched_barrier(0);
  __builtin_amdgcn_s_barrier();

  for (int t = 0; t < NT; ++t) {
    const unsigned short* sb = &lds[t & 3][0];
    s16x8 af[4][2], bfr[2][2];
#pragma unroll
    for (int mt = 0; mt < 4; ++mt)
#pragma unroll
      for (int h = 0; h < 2; ++h)
        af[mt][h] = *(const s16x8*)(sb + offA[mt][h]);
#pragma unroll
    for (int nt = 0; nt < 2; ++nt)
#pragma unroll
      for (int h = 0; h < 2; ++h)
        bfr[nt][h] = *(const s16x8*)(sb + offB[nt][h]);

    if (t + 3 < NT) STAGE((t + 3) & 3);

    if (t + 3 < NT) {
      asm volatile("s_waitcnt vmcnt(8)" ::: "memory");   // tile t+1 landed
    } else if (t + 3 == NT) {
      asm volatile("s_waitcnt vmcnt(4)" ::: "memory");   // drain: t+1 landed
    } else if (t + 2 == NT) {
      asm volatile("s_waitcnt vmcnt(0)" ::: "memory");   // drain: last tile
    }
    __builtin_amdgcn_sched_barrier(0);
    __builtin_amdgcn_s_barrier();

    __builtin_amdgcn_s_setprio(1);
#pragma unroll
    for (int h = 0; h < 2; ++h)
#pragma unroll
      for (int mt = 0; mt < 4; ++mt)
#pragma unroll
        for (int nt = 0; nt < 2; ++nt)
          acc[mt][nt] = __builtin_amdgcn_mfma_f32_32x32x16_bf16(
              af[mt][h], bfr[nt][h], acc[mt][nt], 0, 0, 0);
    __builtin_amdgcn_s_setprio(0);
    __builtin_amdgcn_s_barrier();
  }
#undef STAGE

  // epilogue: 32x32 C/D layout col=lane&31, row=(reg&3)+8*(reg>>2)+4*(lane>>5)
#pragma unroll
  for (int mt = 0; mt < 4; ++mt)
#pragma unroll
    for (int nt = 0; nt < 2; ++nt)
#pragma unroll
      for (int r = 0; r < 16; ++r) {
        int row = bm + wm + mt * 32 + (r & 3) + 8 * (r >> 2) + 4 * lq;
        int col = bn + wn + nt * 32 + lrow;
        float v = acc[mt][nt][r];
        long long idx = (long long)row * N + col;
        if (EPI == 0) {
          Cf[idx] = v;
        } else if (EPI == 1) {
          float s = 1.f / (1.f + __expf(-v));
          Cb[idx] = f2bf(s);
        } else {
          Cb[idx] = f2bf(v);
        }
      }
}

// ---------------- chunked WKV scan (k now bf16) ----------------

#define NEG_INF_F (-1e38f)

__global__ void scan_phase1(const unsigned short* __restrict__ kb,
                            const unsigned short* __restrict__ vb,
                            const float* __restrict__ td,
                            float* __restrict__ locN, float* __restrict__ locD,
                            float* __restrict__ locM,
                            int S, int D, int C, int L) {
  int t = blockIdx.x * blockDim.x + threadIdx.x;  // over B*C*D
  int d = t % D;
  int c = (t / D) % C;
  int b = t / (D * C);
  float w = -__expf(td[d]);
  float num = 0.f, den = 0.f, m = NEG_INF_F;
  long long base = ((long long)(b * S + c * L)) * D + d;
  for (int i = 0; i < L; ++i) {
    float kk = bf2f(kb[base]);
    float vv = bf2f(vb[base]);
    base += D;
    float mn = fmaxf(m + w, kk);
    float e1 = __expf(m + w - mn);
    float e2 = __expf(kk - mn);
    num = e1 * num + e2 * vv;
    den = e1 * den + e2;
    m = mn;
  }
  int o = (b * C + c) * D + d;
  locN[o] = num; locD[o] = den; locM[o] = m;
}

__global__ void scan_phase2(const float* __restrict__ td,
                            const float* __restrict__ locN, const float* __restrict__ locD,
                            const float* __restrict__ locM,
                            float* __restrict__ inN, float* __restrict__ inD,
                            float* __restrict__ inM,
                            int Bc, int D, int C, int L) {
  int t = blockIdx.x * blockDim.x + threadIdx.x;  // over B*D
  if (t >= Bc * D) return;
  int d = t % D, b = t / D;
  float w = -__expf(td[d]);
  float Lw = (float)L * w;
  float num = 0.f, den = 0.f, m = NEG_INF_F;
  for (int c = 0; c < C; ++c) {
    int o = (b * C + c) * D + d;
    inN[o] = num; inD[o] = den; inM[o] = m;
    float sm = m + Lw;                 // decay incoming state over whole chunk
    float lm = locM[o];
    float m2 = fmaxf(sm, lm);
    float e1 = __expf(sm - m2);
    float e2 = __expf(lm - m2);
    num = e1 * num + e2 * locN[o];
    den = e1 * den + e2 * locD[o];
    m = m2;
  }
}

__global__ void scan_phase3(const unsigned short* __restrict__ kb,
                            const unsigned short* __restrict__ vb,
                            const unsigned short* __restrict__ rb,
                            const float* __restrict__ td, const float* __restrict__ tfirst,
                            const float* __restrict__ inN, const float* __restrict__ inD,
                            const float* __restrict__ inM,
                            unsigned short* __restrict__ rr,
                            int S, int D, int C, int L) {
  int t = blockIdx.x * blockDim.x + threadIdx.x;  // over B*C*D
  int d = t % D;
  int c = (t / D) % C;
  int b = t / (D * C);
  float w = -__expf(td[d]);
  float tfd = tfirst[d];
  int o = (b * C + c) * D + d;
  float num = inN[o], den = inD[o], m = inM[o];
  long long base = ((long long)(b * S + c * L)) * D + d;
  for (int i = 0; i < L; ++i) {
    float kk = bf2f(kb[base]);
    float vv = bf2f(vb[base]);
    float rv = bf2f(rb[base]);
    float ktf = kk + tfd;
    float mo = fmaxf(m, ktf);
    float e1 = __expf(m - mo);
    float e2 = __expf(ktf - mo);
    float out = (e1 * num + e2 * vv) / (e1 * den + e2);
    rr[base] = f2bf(out * rv);
    float mn = fmaxf(m + w, kk);
    e1 = __expf(m + w - mn);
    e2 = __expf(kk - mn);
    num = e1 * num + e2 * vv;
    den = e1 * den + e2;
    m = mn;
    base += D;
  }
}

// ---------------- launch ----------------

extern "C" void kernel_launch(void* const* d_in, const int* in_sizes, int n_in,
                              void* d_out, int out_size, void* d_ws, size_t ws_size,
                              hipStream_t stream) {
  const float* hidden = (const float*)d_in[0];
  const float* td  = (const float*)d_in[1];
  const float* tfi = (const float*)d_in[2];
  const float* tmk = (const float*)d_in[3];
  const float* tmv = (const float*)d_in[4];
  const float* tmr = (const float*)d_in[5];
  const float* Wk  = (const float*)d_in[6];
  const float* Wv  = (const float*)d_in[7];
  const float* Wr  = (const float*)d_in[8];
  const float* Wo  = (const float*)d_in[9];
  float* out = (float*)d_out;

  const int H = in_sizes[1];                 // 2048
  const int D = H;
  const long long BS = (long long)in_sizes[0] / H;  // 8192 = B*S
  const int S = 2048;
  const int B = (int)(BS / S);               // 4
  const int C = 32, L = S / C;               // 32 chunks of 64

  // workspace layout (110 MiB, proven safe):
  //   W_b [0,8) | X [8,40) | Y [40,72) | Z [72,104) | states [104,110)
  char* ws = (char*)d_ws;
  const size_t MB = 1u << 20;
  unsigned short* W_b = (unsigned short*)(ws + 0 * MB);
  unsigned short* X   = (unsigned short*)(ws + 8 * MB);
  unsigned short* Y   = (unsigned short*)(ws + 40 * MB);
  unsigned short* Z   = (unsigned short*)(ws + 72 * MB);
  float* locN         = (float*)(ws + 104 * MB);
  float* locD         = (float*)(ws + 105 * MB);
  float* locM         = (float*)(ws + 106 * MB);
  float* inN          = (float*)(ws + 107 * MB);
  float* inD          = (float*)(ws + 108 * MB);
  float* inM          = (float*)(ws + 109 * MB);
  unsigned short* kb  = (unsigned short*)out;   // bf16 k scratch in d_out

  int n4w = H * H / 4;
  int cbk = (n4w + 255) / 256;
  long long total4 = BS * H / 4;
  int pbk = (int)((total4 + 255) / 256);
  int nwg = (int)((BS / 256) * (D / 256));   // 32 * 8 = 256 blocks, 1/CU

  // fused time-shift mix (one pass over hidden)
  prep_mix3<<<pbk, 256, 0, stream>>>((const float4*)hidden,
                                     (const float4*)tmk, (const float4*)tmv, (const float4*)tmr,
                                     (ushort4*)X, (ushort4*)Y, (ushort4*)Z, S, H / 4, total4);

  // k = xk @ Wk^T  (bf16 -> d_out scratch)
  conv_bf16<<<cbk, 256, 0, stream>>>((const float4*)Wk, (ushort4*)W_b, n4w);
  gemm_bt<2><<<nwg, 512, 0, stream>>>(X, W_b, nullptr, kb, (int)BS, D, H);

  // v = xv @ Wv^T  (bf16 -> X)
  conv_bf16<<<cbk, 256, 0, stream>>>((const float4*)Wv, (ushort4*)W_b, n4w);
  gemm_bt<2><<<nwg, 512, 0, stream>>>(Y, W_b, nullptr, X, (int)BS, D, H);

  // r = sigmoid(xr @ Wr^T)  (bf16 -> Y)
  conv_bf16<<<cbk, 256, 0, stream>>>((const float4*)Wr, (ushort4*)W_b, n4w);
  gemm_bt<1><<<nwg, 512, 0, stream>>>(Z, W_b, nullptr, Y, (int)BS, D, H);

  // chunked WKV scan, fused r * rwkv -> Z (bf16)
  int nscan = B * C * D;
  scan_phase1<<<nscan / 256, 256, 0, stream>>>(kb, X, td, locN, locD, locM, S, D, C, L);
  scan_phase2<<<(B * D + 255) / 256, 256, 0, stream>>>(td, locN, locD, locM, inN, inD, inM, B, D, C, L);
  scan_phase3<<<nscan / 256, 256, 0, stream>>>(kb, X, Y, td, tfi, inN, inD, inM, Z, S, D, C, L);

  // out = (r * rwkv) @ Wo^T  (fp32 -> d_out; kb dead now)
  conv_bf16<<<cbk, 256, 0, stream>>>((const float4*)Wo, (ushort4*)W_b, n4w);
  gemm_bt<0><<<nwg, 512, 0, stream>>>(Z, W_b, out, nullptr, (int)BS, H, D);
}

// Round 2
// 554.871 us; speedup vs baseline: 1.1608x; 1.0059x over previous
//
#include <hip/hip_runtime.h>

// ---------------- common helpers ----------------

typedef __attribute__((ext_vector_type(8))) short s16x8;    // 8 x bf16 (4 VGPRs)
typedef __attribute__((ext_vector_type(16))) float f32x16;  // 32x32 MFMA accumulator

__device__ __forceinline__ unsigned short f2bf(float f) {
  union { float f; unsigned u; } v; v.f = f;
  unsigned r = v.u + 0x7fffu + ((v.u >> 16) & 1u);   // round-to-nearest-even
  return (unsigned short)(r >> 16);
}
__device__ __forceinline__ float bf2f(unsigned short h) {
  union { unsigned u; float f; } v; v.u = ((unsigned)h) << 16; return v.f;
}
__device__ __forceinline__ void gload_lds16(const void* g, void* l) {
  __builtin_amdgcn_global_load_lds(
      (const __attribute__((address_space(1))) void*)g,
      (__attribute__((address_space(3))) void*)l, 16, 0, 0);
}

// ---------------- fp32 -> bf16 convert (weights) ----------------

__global__ void conv_bf16(const float4* __restrict__ src, ushort4* __restrict__ dst, int n4) {
  int i = blockIdx.x * blockDim.x + threadIdx.x;
  if (i >= n4) return;
  float4 v = src[i];
  ushort4 o;
  o.x = f2bf(v.x); o.y = f2bf(v.y); o.z = f2bf(v.z); o.w = f2bf(v.w);
  dst[i] = o;
}

// ---------------- fused time-shift mix -> xk, xv, xr (bf16) ----------------

__global__ void prep_mix3(const float4* __restrict__ hidden,
                          const float4* __restrict__ tmk,
                          const float4* __restrict__ tmv,
                          const float4* __restrict__ tmr,
                          ushort4* __restrict__ xk, ushort4* __restrict__ xv,
                          ushort4* __restrict__ xr,
                          int S, int H4, long long total4) {
  long long i = (long long)blockIdx.x * blockDim.x + threadIdx.x;
  if (i >= total4) return;
  int h4 = (int)(i % H4);
  long long sb = i / H4;          // b*S + s
  int s = (int)(sb % S);
  float4 cur = hidden[i];
  float4 prev = make_float4(0.f, 0.f, 0.f, 0.f);
  if (s > 0) prev = hidden[i - H4];
  float4 mk = tmk[h4], mv = tmv[h4], mr = tmr[h4];
  ushort4 ok, ov, orr;
  ok.x = f2bf(cur.x * mk.x + prev.x * (1.f - mk.x));
  ok.y = f2bf(cur.y * mk.y + prev.y * (1.f - mk.y));
  ok.z = f2bf(cur.z * mk.z + prev.z * (1.f - mk.z));
  ok.w = f2bf(cur.w * mk.w + prev.w * (1.f - mk.w));
  ov.x = f2bf(cur.x * mv.x + prev.x * (1.f - mv.x));
  ov.y = f2bf(cur.y * mv.y + prev.y * (1.f - mv.y));
  ov.z = f2bf(cur.z * mv.z + prev.z * (1.f - mv.z));
  ov.w = f2bf(cur.w * mv.w + prev.w * (1.f - mv.w));
  orr.x = f2bf(cur.x * mr.x + prev.x * (1.f - mr.x));
  orr.y = f2bf(cur.y * mr.y + prev.y * (1.f - mr.y));
  orr.z = f2bf(cur.z * mr.z + prev.z * (1.f - mr.z));
  orr.w = f2bf(cur.w * mr.w + prev.w * (1.f - mr.w));
  xk[i] = ok; xv[i] = ov; xr[i] = orr;
}

// ---------------- bf16 NT GEMM: C[M,N] = A[M,K] * B[N,K]^T ----------------
// 256x256 tile, BK=32, 8 waves (2M x 4N, per-wave 128x64 via 4x2 of 32x32x16
// MFMA). Ring-of-4 LDS K-tile slots (128 KiB) + counted s_waitcnt vmcnt(8).
// NEW (this round): each K-step is split into TWO template-shaped phases
// (m201 granularity: 262K FLOP/phase, 2 barriers/phase):
//   phase A: ds_read A-mh0 (4) + B all (4) | stage A-half of t+3 (2 gload) |
//            barrier | setprio(1) 8 MFMA (acc[0..1]) setprio(0) | barrier
//   phase B: ds_read A-mh1 (4)            | stage B-half of t+3 (2 gload) |
//            vmcnt(8) | barrier | setprio(1) 8 MFMA (acc[2..3]) | barrier
// vmcnt(8) proof unchanged: at t.B, loads younger than tile t+1 are exactly
// tiles t+2,t+3 = 8 -> tile t+1 landed before its (t+1).A reads. Ring-4 WAR
// safety unchanged: slot (t+3)&3 = (t-1)&3 is re-written only after the
// barrier ending all reads of tile t-1. Drain: vmcnt 8 -> 4 -> 0 as before.
// EPI: 0 = fp32; 1 = sigmoid bf16; 2 = bf16.

template <int EPI>
__global__ __launch_bounds__(512) void gemm_bt(
    const unsigned short* __restrict__ A, const unsigned short* __restrict__ B,
    float* __restrict__ Cf, unsigned short* __restrict__ Cb,
    int M, int N, int K) {
  // 4 ring slots x (A 256x32 | B 256x32) bf16 = 4 x 32 KiB = 128 KiB
  __shared__ unsigned short lds[4][16384];

  const int tid = threadIdx.x;
  const int wave = tid >> 6;
  const int lane = tid & 63;

  // XCD-aware bijective block swizzle: nwg % 8 == 0 (256 blocks). Each XCD
  // gets a contiguous m-run sharing one B panel (1 MiB, L2-resident).
  const int nwg = (int)gridDim.x;
  const int q = nwg >> 3;
  const int wg = (blockIdx.x & 7) * q + (blockIdx.x >> 3);
  const int GM = M >> 8;
  const int bm = (wg % GM) * 256;
  const int bn = (wg / GM) * 256;

  const int wm = (wave >> 2) * 128;    // wave's 128x64 sub-tile
  const int wn = (wave & 3) * 64;
  const int lrow = lane & 31;
  const int lq = lane >> 5;            // k-chunk half selector (0/1)

  f32x16 acc[4][2] = {};

  // ---- staging addresses (per thread: 4 x 16B per K-tile) ----
  // round covers 128 rows x 64B; thread t: row = t>>2, dest chunk = t&3.
  // inverse swizzle on global source: src chunk = (t&3) ^ ((row>>1)&3).
  const int srow = tid >> 2;
  const int sg = ((tid & 3) ^ ((srow >> 1) & 3)) * 8;
  const unsigned short* gA0 = A + (long long)(bm + srow) * K + sg;
  const unsigned short* gA1 = A + (long long)(bm + 128 + srow) * K + sg;
  const unsigned short* gB0 = B + (long long)(bn + srow) * K + sg;
  const unsigned short* gB1 = B + (long long)(bn + 128 + srow) * K + sg;

#define STAGE_A(sl)                                            \
  {                                                            \
    unsigned short* dst = &lds[sl][0] + wave * 512;            \
    gload_lds16(gA0, dst);                                     \
    gload_lds16(gA1, dst + 4096);                              \
    gA0 += 32; gA1 += 32;                                      \
  }
#define STAGE_B(sl)                                            \
  {                                                            \
    unsigned short* dst = &lds[sl][0] + wave * 512;            \
    gload_lds16(gB0, dst + 8192);                              \
    gload_lds16(gB1, dst + 12288);                             \
    gB0 += 32; gB1 += 32;                                      \
  }

  // ---- fragment LDS offsets (shorts, loop-invariant) ----
  // row R, chunk c (16B) -> R*32 + (c ^ ((R>>1)&3))*8
  int offA[4][2], offB[2][2];
#pragma unroll
  for (int mt = 0; mt < 4; ++mt)
#pragma unroll
    for (int h = 0; h < 2; ++h) {
      int R = wm + mt * 32 + lrow;
      int c = h * 2 + lq;
      offA[mt][h] = R * 32 + ((c ^ ((R >> 1) & 3)) * 8);
    }
#pragma unroll
  for (int nt = 0; nt < 2; ++nt)
#pragma unroll
    for (int h = 0; h < 2; ++h) {
      int Cc = wn + nt * 32 + lrow;
      int c = h * 2 + lq;
      offB[nt][h] = 8192 + Cc * 32 + ((c ^ ((Cc >> 1) & 3)) * 8);
    }

  const int NT = K >> 5;   // K / 32 (= 64 here, >= 4 required)

  // ---- prologue: stage tiles 0,1,2; wait tile 0 landed (8 still in flight)
  STAGE_A(0); STAGE_B(0);
  STAGE_A(1); STAGE_B(1);
  STAGE_A(2); STAGE_B(2);
  asm volatile("s_waitcnt vmcnt(8)" ::: "memory");
  __builtin_amdgcn_sched_barrier(0);
  __builtin_amdgcn_s_barrier();

  for (int t = 0; t < NT; ++t) {
    const unsigned short* sb = &lds[t & 3][0];
    const bool pf = (t + 3 < NT);
    s16x8 af[2][2], bfr[2][2];

    // ======== phase A: A-mh0 + all B-frags; MFMA acc rows 0..63 ========
#pragma unroll
    for (int mt = 0; mt < 2; ++mt)
#pragma unroll
      for (int h = 0; h < 2; ++h)
        af[mt][h] = *(const s16x8*)(sb + offA[mt][h]);
#pragma unroll
    for (int nt = 0; nt < 2; ++nt)
#pragma unroll
      for (int h = 0; h < 2; ++h)
        bfr[nt][h] = *(const s16x8*)(sb + offB[nt][h]);

    if (pf) STAGE_A((t + 3) & 3);
    __builtin_amdgcn_s_barrier();

    __builtin_amdgcn_s_setprio(1);
#pragma unroll
    for (int h = 0; h < 2; ++h)
#pragma unroll
      for (int mt = 0; mt < 2; ++mt)
#pragma unroll
        for (int nt = 0; nt < 2; ++nt)
          acc[mt][nt] = __builtin_amdgcn_mfma_f32_32x32x16_bf16(
              af[mt][h], bfr[nt][h], acc[mt][nt], 0, 0, 0);
    __builtin_amdgcn_s_setprio(0);
    __builtin_amdgcn_s_barrier();

    // ======== phase B: A-mh1 (B-frags live); MFMA acc rows 64..127 ========
    s16x8 ag[2][2];
#pragma unroll
    for (int mt = 0; mt < 2; ++mt)
#pragma unroll
      for (int h = 0; h < 2; ++h)
        ag[mt][h] = *(const s16x8*)(sb + offA[2 + mt][h]);

    if (pf) STAGE_B((t + 3) & 3);

    if (pf) {
      asm volatile("s_waitcnt vmcnt(8)" ::: "memory");   // tile t+1 landed
    } else if (t + 3 == NT) {
      asm volatile("s_waitcnt vmcnt(4)" ::: "memory");   // drain: t+1 landed
    } else if (t + 2 == NT) {
      asm volatile("s_waitcnt vmcnt(0)" ::: "memory");   // drain: last tile
    }
    __builtin_amdgcn_sched_barrier(0);
    __builtin_amdgcn_s_barrier();

    __builtin_amdgcn_s_setprio(1);
#pragma unroll
    for (int h = 0; h < 2; ++h)
#pragma unroll
      for (int mt = 0; mt < 2; ++mt)
#pragma unroll
        for (int nt = 0; nt < 2; ++nt)
          acc[2 + mt][nt] = __builtin_amdgcn_mfma_f32_32x32x16_bf16(
              ag[mt][h], bfr[nt][h], acc[2 + mt][nt], 0, 0, 0);
    __builtin_amdgcn_s_setprio(0);
    __builtin_amdgcn_s_barrier();
  }
#undef STAGE_A
#undef STAGE_B

  // epilogue: 32x32 C/D layout col=lane&31, row=(reg&3)+8*(reg>>2)+4*(lane>>5)
#pragma unroll
  for (int mt = 0; mt < 4; ++mt)
#pragma unroll
    for (int nt = 0; nt < 2; ++nt)
#pragma unroll
      for (int r = 0; r < 16; ++r) {
        int row = bm + wm + mt * 32 + (r & 3) + 8 * (r >> 2) + 4 * lq;
        int col = bn + wn + nt * 32 + lrow;
        float v = acc[mt][nt][r];
        long long idx = (long long)row * N + col;
        if (EPI == 0) {
          Cf[idx] = v;
        } else if (EPI == 1) {
          float s = 1.f / (1.f + __expf(-v));
          Cb[idx] = f2bf(s);
        } else {
          Cb[idx] = f2bf(v);
        }
      }
}

// ---------------- chunked WKV scan (k now bf16) ----------------

#define NEG_INF_F (-1e38f)

__global__ void scan_phase1(const unsigned short* __restrict__ kb,
                            const unsigned short* __restrict__ vb,
                            const float* __restrict__ td,
                            float* __restrict__ locN, float* __restrict__ locD,
                            float* __restrict__ locM,
                            int S, int D, int C, int L) {
  int t = blockIdx.x * blockDim.x + threadIdx.x;  // over B*C*D
  int d = t % D;
  int c = (t / D) % C;
  int b = t / (D * C);
  float w = -__expf(td[d]);
  float num = 0.f, den = 0.f, m = NEG_INF_F;
  long long base = ((long long)(b * S + c * L)) * D + d;
  for (int i = 0; i < L; ++i) {
    float kk = bf2f(kb[base]);
    float vv = bf2f(vb[base]);
    base += D;
    float mn = fmaxf(m + w, kk);
    float e1 = __expf(m + w - mn);
    float e2 = __expf(kk - mn);
    num = e1 * num + e2 * vv;
    den = e1 * den + e2;
    m = mn;
  }
  int o = (b * C + c) * D + d;
  locN[o] = num; locD[o] = den; locM[o] = m;
}

__global__ void scan_phase2(const float* __restrict__ td,
                            const float* __restrict__ locN, const float* __restrict__ locD,
                            const float* __restrict__ locM,
                            float* __restrict__ inN, float* __restrict__ inD,
                            float* __restrict__ inM,
                            int Bc, int D, int C, int L) {
  int t = blockIdx.x * blockDim.x + threadIdx.x;  // over B*D
  if (t >= Bc * D) return;
  int d = t % D, b = t / D;
  float w = -__expf(td[d]);
  float Lw = (float)L * w;
  float num = 0.f, den = 0.f, m = NEG_INF_F;
  for (int c = 0; c < C; ++c) {
    int o = (b * C + c) * D + d;
    inN[o] = num; inD[o] = den; inM[o] = m;
    float sm = m + Lw;                 // decay incoming state over whole chunk
    float lm = locM[o];
    float m2 = fmaxf(sm, lm);
    float e1 = __expf(sm - m2);
    float e2 = __expf(lm - m2);
    num = e1 * num + e2 * locN[o];
    den = e1 * den + e2 * locD[o];
    m = m2;
  }
}

__global__ void scan_phase3(const unsigned short* __restrict__ kb,
                            const unsigned short* __restrict__ vb,
                            const unsigned short* __restrict__ rb,
                            const float* __restrict__ td, const float* __restrict__ tfirst,
                            const float* __restrict__ inN, const float* __restrict__ inD,
                            const float* __restrict__ inM,
                            unsigned short* __restrict__ rr,
                            int S, int D, int C, int L) {
  int t = blockIdx.x * blockDim.x + threadIdx.x;  // over B*C*D
  int d = t % D;
  int c = (t / D) % C;
  int b = t / (D * C);
  float w = -__expf(td[d]);
  float tfd = tfirst[d];
  int o = (b * C + c) * D + d;
  float num = inN[o], den = inD[o], m = inM[o];
  long long base = ((long long)(b * S + c * L)) * D + d;
  for (int i = 0; i < L; ++i) {
    float kk = bf2f(kb[base]);
    float vv = bf2f(vb[base]);
    float rv = bf2f(rb[base]);
    float ktf = kk + tfd;
    float mo = fmaxf(m, ktf);
    float e1 = __expf(m - mo);
    float e2 = __expf(ktf - mo);
    float out = (e1 * num + e2 * vv) / (e1 * den + e2);
    rr[base] = f2bf(out * rv);
    float mn = fmaxf(m + w, kk);
    e1 = __expf(m + w - mn);
    e2 = __expf(kk - mn);
    num = e1 * num + e2 * vv;
    den = e1 * den + e2;
    m = mn;
    base += D;
  }
}

// ---------------- launch ----------------

extern "C" void kernel_launch(void* const* d_in, const int* in_sizes, int n_in,
                              void* d_out, int out_size, void* d_ws, size_t ws_size,
                              hipStream_t stream) {
  const float* hidden = (const float*)d_in[0];
  const float* td  = (const float*)d_in[1];
  const float* tfi = (const float*)d_in[2];
  const float* tmk = (const float*)d_in[3];
  const float* tmv = (const float*)d_in[4];
  const float* tmr = (const float*)d_in[5];
  const float* Wk  = (const float*)d_in[6];
  const float* Wv  = (const float*)d_in[7];
  const float* Wr  = (const float*)d_in[8];
  const float* Wo  = (const float*)d_in[9];
  float* out = (float*)d_out;

  const int H = in_sizes[1];                 // 2048
  const int D = H;
  const long long BS = (long long)in_sizes[0] / H;  // 8192 = B*S
  const int S = 2048;
  const int B = (int)(BS / S);               // 4
  const int C = 32, L = S / C;               // 32 chunks of 64

  // workspace layout (110 MiB, proven safe):
  //   W_b [0,8) | X [8,40) | Y [40,72) | Z [72,104) | states [104,110)
  char* ws = (char*)d_ws;
  const size_t MB = 1u << 20;
  unsigned short* W_b = (unsigned short*)(ws + 0 * MB);
  unsigned short* X   = (unsigned short*)(ws + 8 * MB);
  unsigned short* Y   = (unsigned short*)(ws + 40 * MB);
  unsigned short* Z   = (unsigned short*)(ws + 72 * MB);
  float* locN         = (float*)(ws + 104 * MB);
  float* locD         = (float*)(ws + 105 * MB);
  float* locM         = (float*)(ws + 106 * MB);
  float* inN          = (float*)(ws + 107 * MB);
  float* inD          = (float*)(ws + 108 * MB);
  float* inM          = (float*)(ws + 109 * MB);
  unsigned short* kb  = (unsigned short*)out;   // bf16 k scratch in d_out

  int n4w = H * H / 4;
  int cbk = (n4w + 255) / 256;
  long long total4 = BS * H / 4;
  int pbk = (int)((total4 + 255) / 256);
  int nwg = (int)((BS / 256) * (D / 256));   // 32 * 8 = 256 blocks, 1/CU

  // fused time-shift mix (one pass over hidden)
  prep_mix3<<<pbk, 256, 0, stream>>>((const float4*)hidden,
                                     (const float4*)tmk, (const float4*)tmv, (const float4*)tmr,
                                     (ushort4*)X, (ushort4*)Y, (ushort4*)Z, S, H / 4, total4);

  // k = xk @ Wk^T  (bf16 -> d_out scratch)
  conv_bf16<<<cbk, 256, 0, stream>>>((const float4*)Wk, (ushort4*)W_b, n4w);
  gemm_bt<2><<<nwg, 512, 0, stream>>>(X, W_b, nullptr, kb, (int)BS, D, H);

  // v = xv @ Wv^T  (bf16 -> X)
  conv_bf16<<<cbk, 256, 0, stream>>>((const float4*)Wv, (ushort4*)W_b, n4w);
  gemm_bt<2><<<nwg, 512, 0, stream>>>(Y, W_b, nullptr, X, (int)BS, D, H);

  // r = sigmoid(xr @ Wr^T)  (bf16 -> Y)
  conv_bf16<<<cbk, 256, 0, stream>>>((const float4*)Wr, (ushort4*)W_b, n4w);
  gemm_bt<1><<<nwg, 512, 0, stream>>>(Z, W_b, nullptr, Y, (int)BS, D, H);

  // chunked WKV scan, fused r * rwkv -> Z (bf16)
  int nscan = B * C * D;
  scan_phase1<<<nscan / 256, 256, 0, stream>>>(kb, X, td, locN, locD, locM, S, D, C, L);
  scan_phase2<<<(B * D + 255) / 256, 256, 0, stream>>>(td, locN, locD, locM, inN, inD, inM, B, D, C, L);
  scan_phase3<<<nscan / 256, 256, 0, stream>>>(kb, X, Y, td, tfi, inN, inD, inM, Z, S, D, C, L);

  // out = (r * rwkv) @ Wo^T  (fp32 -> d_out; kb dead now)
  conv_bf16<<<cbk, 256, 0, stream>>>((const float4*)Wo, (ushort4*)W_b, n4w);
  gemm_bt<0><<<nwg, 512, 0, stream>>>(Z, W_b, out, nullptr, (int)BS, H, D);
}

// Round 3
// 551.279 us; speedup vs baseline: 1.1683x; 1.0065x over previous
//
#include <hip/hip_runtime.h>

// ---------------- common helpers ----------------

typedef __attribute__((ext_vector_type(8))) short s16x8;    // 8 x bf16 (4 VGPRs)
typedef __attribute__((ext_vector_type(16))) float f32x16;  // 32x32 MFMA accumulator

__device__ __forceinline__ unsigned short f2bf(float f) {
  union { float f; unsigned u; } v; v.f = f;
  unsigned r = v.u + 0x7fffu + ((v.u >> 16) & 1u);   // round-to-nearest-even
  return (unsigned short)(r >> 16);
}
__device__ __forceinline__ float bf2f(unsigned short h) {
  union { unsigned u; float f; } v; v.u = ((unsigned)h) << 16; return v.f;
}
__device__ __forceinline__ void gload_lds16(const void* g, void* l) {
  __builtin_amdgcn_global_load_lds(
      (const __attribute__((address_space(1))) void*)g,
      (__attribute__((address_space(3))) void*)l, 16, 0, 0);
}

// ---------------- fp32 -> bf16 convert (weights) ----------------

__global__ void conv_bf16(const float4* __restrict__ src, ushort4* __restrict__ dst, int n4) {
  int i = blockIdx.x * blockDim.x + threadIdx.x;
  if (i >= n4) return;
  float4 v = src[i];
  ushort4 o;
  o.x = f2bf(v.x); o.y = f2bf(v.y); o.z = f2bf(v.z); o.w = f2bf(v.w);
  dst[i] = o;
}

// ---------------- fused time-shift mix -> xk, xv, xr (bf16) ----------------

__global__ void prep_mix3(const float4* __restrict__ hidden,
                          const float4* __restrict__ tmk,
                          const float4* __restrict__ tmv,
                          const float4* __restrict__ tmr,
                          ushort4* __restrict__ xk, ushort4* __restrict__ xv,
                          ushort4* __restrict__ xr,
                          int S, int H4, long long total4) {
  long long i = (long long)blockIdx.x * blockDim.x + threadIdx.x;
  if (i >= total4) return;
  int h4 = (int)(i % H4);
  long long sb = i / H4;          // b*S + s
  int s = (int)(sb % S);
  float4 cur = hidden[i];
  float4 prev = make_float4(0.f, 0.f, 0.f, 0.f);
  if (s > 0) prev = hidden[i - H4];
  float4 mk = tmk[h4], mv = tmv[h4], mr = tmr[h4];
  ushort4 ok, ov, orr;
  ok.x = f2bf(cur.x * mk.x + prev.x * (1.f - mk.x));
  ok.y = f2bf(cur.y * mk.y + prev.y * (1.f - mk.y));
  ok.z = f2bf(cur.z * mk.z + prev.z * (1.f - mk.z));
  ok.w = f2bf(cur.w * mk.w + prev.w * (1.f - mk.w));
  ov.x = f2bf(cur.x * mv.x + prev.x * (1.f - mv.x));
  ov.y = f2bf(cur.y * mv.y + prev.y * (1.f - mv.y));
  ov.z = f2bf(cur.z * mv.z + prev.z * (1.f - mv.z));
  ov.w = f2bf(cur.w * mv.w + prev.w * (1.f - mv.w));
  orr.x = f2bf(cur.x * mr.x + prev.x * (1.f - mr.x));
  orr.y = f2bf(cur.y * mr.y + prev.y * (1.f - mr.y));
  orr.z = f2bf(cur.z * mr.z + prev.z * (1.f - mr.z));
  orr.w = f2bf(cur.w * mr.w + prev.w * (1.f - mr.w));
  xk[i] = ok; xv[i] = ov; xr[i] = orr;
}

// ---------------- bf16 NT GEMM: C[M,N] = A[M,K] * B[N,K]^T ----------------
// 256x256 tile, BK=32, 8 waves (2M x 4N, per-wave 128x64 via 4x2 of 32x32x16
// MFMA). Ring-of-4 LDS K-tile slots (128 KiB) + counted s_waitcnt vmcnt(8),
// 2 barriers per K-step (round-1 skeleton, 86.6us verified).
// NEW: register-level software pipeline (the actual m201 mechanism): every
// MFMA cluster consumes fragments whose ds_reads were ISSUED one half-step
// earlier, so LDS latency hides under the previous cluster's MFMA:
//   phase A: STAGE_A(t+3) | issue a1 reads (A-mh1, tile t)
//            | MFMA acc[0..1] on a0[P],bfr (issued last half-step)
//   phase B: STAGE_B(t+3) | vmcnt(8) | barrier (tile t+1 visible)
//            | issue a0[Q] reads (A-mh0, tile t+1)
//            | MFMA acc[2..3] on a1,bfr
//            | issue bfr reads (B, tile t+1; after cluster - in-order WAR safe)
//            | barrier
// vmcnt(8) proof: at t.B outstanding = tiles t+2 (4) + t+3 (4) younger than
// tile t+1 -> vmcnt(8) lands tile t+1. Drain 8->4->0 unchanged. Ring-4 WAR:
// all reads of slot s&3 (a0/bfr at s-1.B, a1 at s.A) are lgkmcnt-waited
// before s's end-barrier, and slot s&3 is re-staged only at s+1.A, after it.
// Ping-pong a0 uses literal indices via x2 unroll (NT even); bfr/a1 single-
// buffered (reads issued after their last consumer) to stay <=256 unified
// regs at 2 waves/SIMD. EPI: 0 = fp32; 1 = sigmoid bf16; 2 = bf16.

template <int EPI>
__global__ __launch_bounds__(512, 2) void gemm_bt(
    const unsigned short* __restrict__ A, const unsigned short* __restrict__ B,
    float* __restrict__ Cf, unsigned short* __restrict__ Cb,
    int M, int N, int K) {
  // 4 ring slots x (A 256x32 | B 256x32) bf16 = 4 x 32 KiB = 128 KiB
  __shared__ unsigned short lds[4][16384];

  const int tid = threadIdx.x;
  const int wave = tid >> 6;
  const int lane = tid & 63;

  // XCD-aware bijective block swizzle: nwg % 8 == 0 (256 blocks).
  const int nwg = (int)gridDim.x;
  const int q = nwg >> 3;
  const int wg = (blockIdx.x & 7) * q + (blockIdx.x >> 3);
  const int GM = M >> 8;
  const int bm = (wg % GM) * 256;
  const int bn = (wg / GM) * 256;

  const int wm = (wave >> 2) * 128;    // wave's 128x64 sub-tile
  const int wn = (wave & 3) * 64;
  const int lrow = lane & 31;
  const int lq = lane >> 5;            // k-chunk half selector (0/1)

  f32x16 acc[4][2] = {};

  // ---- staging addresses (per thread: 4 x 16B per K-tile) ----
  const int srow = tid >> 2;
  const int sg = ((tid & 3) ^ ((srow >> 1) & 3)) * 8;
  const unsigned short* gA0 = A + (long long)(bm + srow) * K + sg;
  const unsigned short* gA1 = A + (long long)(bm + 128 + srow) * K + sg;
  const unsigned short* gB0 = B + (long long)(bn + srow) * K + sg;
  const unsigned short* gB1 = B + (long long)(bn + 128 + srow) * K + sg;

#define STAGE_A(sl)                                            \
  {                                                            \
    unsigned short* dst = &lds[sl][0] + wave * 512;            \
    gload_lds16(gA0, dst);                                     \
    gload_lds16(gA1, dst + 4096);                              \
    gA0 += 32; gA1 += 32;                                      \
  }
#define STAGE_B(sl)                                            \
  {                                                            \
    unsigned short* dst = &lds[sl][0] + wave * 512;            \
    gload_lds16(gB0, dst + 8192);                              \
    gload_lds16(gB1, dst + 12288);                             \
    gB0 += 32; gB1 += 32;                                      \
  }

  // ---- fragment LDS offsets (shorts, loop-invariant) ----
  // row R, chunk c (16B) -> R*32 + (c ^ ((R>>1)&3))*8
  int offA[4][2], offB[2][2];
#pragma unroll
  for (int mt = 0; mt < 4; ++mt)
#pragma unroll
    for (int h = 0; h < 2; ++h) {
      int R = wm + mt * 32 + lrow;
      int c = h * 2 + lq;
      offA[mt][h] = R * 32 + ((c ^ ((R >> 1) & 3)) * 8);
    }
#pragma unroll
  for (int nt = 0; nt < 2; ++nt)
#pragma unroll
    for (int h = 0; h < 2; ++h) {
      int Cc = wn + nt * 32 + lrow;
      int c = h * 2 + lq;
      offB[nt][h] = 8192 + Cc * 32 + ((c ^ ((Cc >> 1) & 3)) * 8);
    }

  const int NT = K >> 5;   // K / 32 (= 64 here; even, >= 4 required)

  // fragment registers: a0 ping-pong (tile t / t+1), a1 + bfr single-buffered
  s16x8 a0[2][2][2];   // [pp][mt(0..1)][h]
  s16x8 a1[2][2];      // A-mh1 of current tile
  s16x8 bfr[2][2];     // B frags of current tile

  // ---- prologue: stage tiles 0,1,2; tile 0 landed; read its set0 ----
  STAGE_A(0); STAGE_B(0);
  STAGE_A(1); STAGE_B(1);
  STAGE_A(2); STAGE_B(2);
  asm volatile("s_waitcnt vmcnt(8)" ::: "memory");
  __builtin_amdgcn_sched_barrier(0);
  __builtin_amdgcn_s_barrier();
  __builtin_amdgcn_sched_barrier(0);
#pragma unroll
  for (int mt = 0; mt < 2; ++mt)
#pragma unroll
    for (int h = 0; h < 2; ++h)
      a0[0][mt][h] = *(const s16x8*)(&lds[0][0] + offA[mt][h]);
#pragma unroll
  for (int nt = 0; nt < 2; ++nt)
#pragma unroll
    for (int h = 0; h < 2; ++h)
      bfr[nt][h] = *(const s16x8*)(&lds[0][0] + offB[nt][h]);

#define K_ITER(T, P, Q)                                                       \
  {                                                                           \
    const int t_ = (T);                                                       \
    const unsigned short* sb = &lds[t_ & 3][0];                               \
    const unsigned short* sbn = &lds[(t_ + 1) & 3][0];                        \
    const bool pf = (t_ + 3 < NT);                                            \
    const bool rd = (t_ + 1 < NT);                                            \
    /* ---- phase A ---- */                                                   \
    if (pf) STAGE_A((t_ + 3) & 3);                                            \
    _Pragma("unroll") for (int mt = 0; mt < 2; ++mt)                          \
      _Pragma("unroll") for (int h = 0; h < 2; ++h)                           \
        a1[mt][h] = *(const s16x8*)(sb + offA[2 + mt][h]);                    \
    __builtin_amdgcn_s_setprio(1);                                            \
    _Pragma("unroll") for (int h = 0; h < 2; ++h)                             \
      _Pragma("unroll") for (int mt = 0; mt < 2; ++mt)                        \
        _Pragma("unroll") for (int nt = 0; nt < 2; ++nt)                      \
          acc[mt][nt] = __builtin_amdgcn_mfma_f32_32x32x16_bf16(              \
              a0[P][mt][h], bfr[nt][h], acc[mt][nt], 0, 0, 0);                \
    __builtin_amdgcn_s_setprio(0);                                            \
    /* ---- phase B ---- */                                                   \
    if (pf) STAGE_B((t_ + 3) & 3);                                            \
    if (pf) {                                                                 \
      asm volatile("s_waitcnt vmcnt(8)" ::: "memory");                        \
    } else if (t_ + 3 == NT) {                                                \
      asm volatile("s_waitcnt vmcnt(4)" ::: "memory");                        \
    } else if (t_ + 2 == NT) {                                                \
      asm volatile("s_waitcnt vmcnt(0)" ::: "memory");                        \
    }                                                                         \
    __builtin_amdgcn_sched_barrier(0);                                        \
    __builtin_amdgcn_s_barrier();                                             \
    __builtin_amdgcn_sched_barrier(0);                                        \
    if (rd) {                                                                 \
      _Pragma("unroll") for (int mt = 0; mt < 2; ++mt)                        \
        _Pragma("unroll") for (int h = 0; h < 2; ++h)                         \
          a0[Q][mt][h] = *(const s16x8*)(sbn + offA[mt][h]);                  \
    }                                                                         \
    __builtin_amdgcn_s_setprio(1);                                            \
    _Pragma("unroll") for (int h = 0; h < 2; ++h)                             \
      _Pragma("unroll") for (int mt = 0; mt < 2; ++mt)                        \
        _Pragma("unroll") for (int nt = 0; nt < 2; ++nt)                      \
          acc[2 + mt][nt] = __builtin_amdgcn_mfma_f32_32x32x16_bf16(          \
              a1[mt][h], bfr[nt][h], acc[2 + mt][nt], 0, 0, 0);               \
    __builtin_amdgcn_s_setprio(0);                                            \
    if (rd) {                                                                 \
      _Pragma("unroll") for (int nt = 0; nt < 2; ++nt)                        \
        _Pragma("unroll") for (int h = 0; h < 2; ++h)                         \
          bfr[nt][h] = *(const s16x8*)(sbn + offB[nt][h]);                    \
    }                                                                         \
    __builtin_amdgcn_s_barrier();                                             \
  }

  for (int t = 0; t < NT; t += 2) {
    K_ITER(t, 0, 1);
    K_ITER(t + 1, 1, 0);
  }
#undef K_ITER
#undef STAGE_A
#undef STAGE_B

  // epilogue: 32x32 C/D layout col=lane&31, row=(reg&3)+8*(reg>>2)+4*(lane>>5)
#pragma unroll
  for (int mt = 0; mt < 4; ++mt)
#pragma unroll
    for (int nt = 0; nt < 2; ++nt)
#pragma unroll
      for (int r = 0; r < 16; ++r) {
        int row = bm + wm + mt * 32 + (r & 3) + 8 * (r >> 2) + 4 * lq;
        int col = bn + wn + nt * 32 + lrow;
        float v = acc[mt][nt][r];
        long long idx = (long long)row * N + col;
        if (EPI == 0) {
          Cf[idx] = v;
        } else if (EPI == 1) {
          float s = 1.f / (1.f + __expf(-v));
          Cb[idx] = f2bf(s);
        } else {
          Cb[idx] = f2bf(v);
        }
      }
}

// ---------------- chunked WKV scan (k now bf16) ----------------

#define NEG_INF_F (-1e38f)

__global__ void scan_phase1(const unsigned short* __restrict__ kb,
                            const unsigned short* __restrict__ vb,
                            const float* __restrict__ td,
                            float* __restrict__ locN, float* __restrict__ locD,
                            float* __restrict__ locM,
                            int S, int D, int C, int L) {
  int t = blockIdx.x * blockDim.x + threadIdx.x;  // over B*C*D
  int d = t % D;
  int c = (t / D) % C;
  int b = t / (D * C);
  float w = -__expf(td[d]);
  float num = 0.f, den = 0.f, m = NEG_INF_F;
  long long base = ((long long)(b * S + c * L)) * D + d;
  for (int i = 0; i < L; ++i) {
    float kk = bf2f(kb[base]);
    float vv = bf2f(vb[base]);
    base += D;
    float mn = fmaxf(m + w, kk);
    float e1 = __expf(m + w - mn);
    float e2 = __expf(kk - mn);
    num = e1 * num + e2 * vv;
    den = e1 * den + e2;
    m = mn;
  }
  int o = (b * C + c) * D + d;
  locN[o] = num; locD[o] = den; locM[o] = m;
}

__global__ void scan_phase2(const float* __restrict__ td,
                            const float* __restrict__ locN, const float* __restrict__ locD,
                            const float* __restrict__ locM,
                            float* __restrict__ inN, float* __restrict__ inD,
                            float* __restrict__ inM,
                            int Bc, int D, int C, int L) {
  int t = blockIdx.x * blockDim.x + threadIdx.x;  // over B*D
  if (t >= Bc * D) return;
  int d = t % D, b = t / D;
  float w = -__expf(td[d]);
  float Lw = (float)L * w;
  float num = 0.f, den = 0.f, m = NEG_INF_F;
  for (int c = 0; c < C; ++c) {
    int o = (b * C + c) * D + d;
    inN[o] = num; inD[o] = den; inM[o] = m;
    float sm = m + Lw;                 // decay incoming state over whole chunk
    float lm = locM[o];
    float m2 = fmaxf(sm, lm);
    float e1 = __expf(sm - m2);
    float e2 = __expf(lm - m2);
    num = e1 * num + e2 * locN[o];
    den = e1 * den + e2 * locD[o];
    m = m2;
  }
}

__global__ void scan_phase3(const unsigned short* __restrict__ kb,
                            const unsigned short* __restrict__ vb,
                            const unsigned short* __restrict__ rb,
                            const float* __restrict__ td, const float* __restrict__ tfirst,
                            const float* __restrict__ inN, const float* __restrict__ inD,
                            const float* __restrict__ inM,
                            unsigned short* __restrict__ rr,
                            int S, int D, int C, int L) {
  int t = blockIdx.x * blockDim.x + threadIdx.x;  // over B*C*D
  int d = t % D;
  int c = (t / D) % C;
  int b = t / (D * C);
  float w = -__expf(td[d]);
  float tfd = tfirst[d];
  int o = (b * C + c) * D + d;
  float num = inN[o], den = inD[o], m = inM[o];
  long long base = ((long long)(b * S + c * L)) * D + d;
  for (int i = 0; i < L; ++i) {
    float kk = bf2f(kb[base]);
    float vv = bf2f(vb[base]);
    float rv = bf2f(rb[base]);
    float ktf = kk + tfd;
    float mo = fmaxf(m, ktf);
    float e1 = __expf(m - mo);
    float e2 = __expf(ktf - mo);
    float out = (e1 * num + e2 * vv) / (e1 * den + e2);
    rr[base] = f2bf(out * rv);
    float mn = fmaxf(m + w, kk);
    e1 = __expf(m + w - mn);
    e2 = __expf(kk - mn);
    num = e1 * num + e2 * vv;
    den = e1 * den + e2;
    m = mn;
    base += D;
  }
}

// ---------------- launch ----------------

extern "C" void kernel_launch(void* const* d_in, const int* in_sizes, int n_in,
                              void* d_out, int out_size, void* d_ws, size_t ws_size,
                              hipStream_t stream) {
  const float* hidden = (const float*)d_in[0];
  const float* td  = (const float*)d_in[1];
  const float* tfi = (const float*)d_in[2];
  const float* tmk = (const float*)d_in[3];
  const float* tmv = (const float*)d_in[4];
  const float* tmr = (const float*)d_in[5];
  const float* Wk  = (const float*)d_in[6];
  const float* Wv  = (const float*)d_in[7];
  const float* Wr  = (const float*)d_in[8];
  const float* Wo  = (const float*)d_in[9];
  float* out = (float*)d_out;

  const int H = in_sizes[1];                 // 2048
  const int D = H;
  const long long BS = (long long)in_sizes[0] / H;  // 8192 = B*S
  const int S = 2048;
  const int B = (int)(BS / S);               // 4
  const int C = 32, L = S / C;               // 32 chunks of 64

  // workspace layout (110 MiB, proven safe):
  //   W_b [0,8) | X [8,40) | Y [40,72) | Z [72,104) | states [104,110)
  char* ws = (char*)d_ws;
  const size_t MB = 1u << 20;
  unsigned short* W_b = (unsigned short*)(ws + 0 * MB);
  unsigned short* X   = (unsigned short*)(ws + 8 * MB);
  unsigned short* Y   = (unsigned short*)(ws + 40 * MB);
  unsigned short* Z   = (unsigned short*)(ws + 72 * MB);
  float* locN         = (float*)(ws + 104 * MB);
  float* locD         = (float*)(ws + 105 * MB);
  float* locM         = (float*)(ws + 106 * MB);
  float* inN          = (float*)(ws + 107 * MB);
  float* inD          = (float*)(ws + 108 * MB);
  float* inM          = (float*)(ws + 109 * MB);
  unsigned short* kb  = (unsigned short*)out;   // bf16 k scratch in d_out

  int n4w = H * H / 4;
  int cbk = (n4w + 255) / 256;
  long long total4 = BS * H / 4;
  int pbk = (int)((total4 + 255) / 256);
  int nwg = (int)((BS / 256) * (D / 256));   // 32 * 8 = 256 blocks, 1/CU

  // fused time-shift mix (one pass over hidden)
  prep_mix3<<<pbk, 256, 0, stream>>>((const float4*)hidden,
                                     (const float4*)tmk, (const float4*)tmv, (const float4*)tmr,
                                     (ushort4*)X, (ushort4*)Y, (ushort4*)Z, S, H / 4, total4);

  // k = xk @ Wk^T  (bf16 -> d_out scratch)
  conv_bf16<<<cbk, 256, 0, stream>>>((const float4*)Wk, (ushort4*)W_b, n4w);
  gemm_bt<2><<<nwg, 512, 0, stream>>>(X, W_b, nullptr, kb, (int)BS, D, H);

  // v = xv @ Wv^T  (bf16 -> X)
  conv_bf16<<<cbk, 256, 0, stream>>>((const float4*)Wv, (ushort4*)W_b, n4w);
  gemm_bt<2><<<nwg, 512, 0, stream>>>(Y, W_b, nullptr, X, (int)BS, D, H);

  // r = sigmoid(xr @ Wr^T)  (bf16 -> Y)
  conv_bf16<<<cbk, 256, 0, stream>>>((const float4*)Wr, (ushort4*)W_b, n4w);
  gemm_bt<1><<<nwg, 512, 0, stream>>>(Z, W_b, nullptr, Y, (int)BS, D, H);

  // chunked WKV scan, fused r * rwkv -> Z (bf16)
  int nscan = B * C * D;
  scan_phase1<<<nscan / 256, 256, 0, stream>>>(kb, X, td, locN, locD, locM, S, D, C, L);
  scan_phase2<<<(B * D + 255) / 256, 256, 0, stream>>>(td, locN, locD, locM, inN, inD, inM, B, D, C, L);
  scan_phase3<<<nscan / 256, 256, 0, stream>>>(kb, X, Y, td, tfi, inN, inD, inM, Z, S, D, C, L);

  // out = (r * rwkv) @ Wo^T  (fp32 -> d_out; kb dead now)
  conv_bf16<<<cbk, 256, 0, stream>>>((const float4*)Wo, (ushort4*)W_b, n4w);
  gemm_bt<0><<<nwg, 512, 0, stream>>>(Z, W_b, out, nullptr, (int)BS, H, D);
}